// Round 5
// baseline (22.213 us; speedup 1.0000x reference)
//
#include <hip/hip_runtime.h>
#include <math.h>

#define NB 32
#define NA 3
#define NC 80
#define NH 56
#define NW 56
#define NT 50
#define HW (NH*NW)              // 3136
#define CELLS_PER_B (NA*HW)     // 9408
#define CH_PER_A (5+NC)         // 85
#define EPSF 1e-7f
#define NBX 19                  // x-blocks per batch
#define HALF (NBX*256)          // 4864; thread handles c0 and c0+HALF
#define NBLK (NBX*NB)           // 608
#define MAPW (CELLS_PER_B/4)    // 2352 words

__device__ __forceinline__ float fsig(float v) { return 1.0f / (1.0f + __expf(-v)); }

// ---------------------------------------------------------------------------
// Fused kernel. grid (19, 32), block 256, 2 cells/thread.
// Phase 0: zero LDS cell->target byte map; prep 50 targets into LDS;
//          thread 0 serially scatters map[flat[t]] = t+1 (last-t wins, exact
//          .at[].set duplicate semantics).
// Phase 1: dense pass over 2 cells/thread — silence test via min/max-form
//          intersection + prescaled areas (no div, no per-iter tsel compare).
// Phase 2: class focal loss for this block's object cells (3 obj x 80 cls lanes).
// Phase 3: block reduce -> one float4 partial per block (no global atomics).
// ---------------------------------------------------------------------------
__global__ __launch_bounds__(256) void fused_kernel(const float* __restrict__ out,
                                                    const float* __restrict__ tb,
                                                    const float* __restrict__ tcls,
                                                    const float* __restrict__ cwt,
                                                    float4* __restrict__ part) {
    __shared__ float4 sp1[NT];                 // {x1, x2, y1, y2}
    __shared__ float  sq[NT];                  // 0.375 * area_t
    __shared__ int    s_flat[NT];
    __shared__ unsigned char s_map[CELLS_PER_B];
    __shared__ int    s_obj[NT];
    __shared__ int    s_cnt;
    __shared__ float  redm[4], redc[4];

    const int b = blockIdx.y;
    const int tid = threadIdx.x;

    const float aw[3]  = {1.28967f, 2.12714f, 3.27212f};
    const float ah[3]  = {4.15014f, 5.09344f, 5.87423f};
    const float law[3] = {0.25438842f, 0.75477730f, 1.18543813f};   // ln(aw)
    const float lah[3] = {1.42314173f, 1.62795138f, 1.77057764f};   // ln(ah)

    // ---- Phase 0 ----
    unsigned int* mw = (unsigned int*)s_map;
    #pragma unroll
    for (int k = 0; k < 10; ++k) {
        int idx = tid + k * 256;
        if (idx < MAPW) mw[idx] = 0u;
    }
    if (tid == 0) s_cnt = 0;

    if (tid < NT) {
        float4 box = ((const float4*)tb)[b * NT + tid];
        if (box.z > 0.0f) {
            float gx = box.x * (float)NW;
            float gy = box.y * (float)NH;
            float gw = box.z * (float)NW;
            float gh = box.w * (float)NH;
            sp1[tid] = make_float4(gx - 0.5f * gw, gx + 0.5f * gw,
                                   gy - 0.5f * gh, gy + 0.5f * gh);
            sq[tid] = 0.375f * gw * gh;
            int bn = 0; float best = -1.0f;
            #pragma unroll
            for (int k = 0; k < 3; ++k) {
                float inter = fminf(aw[k], gw) * fminf(ah[k], gh);
                float uni = aw[k] * ah[k] + gw * gh - inter;
                float r = inter / uni;
                if (r > best) { best = r; bn = k; }
            }
            int gi = (int)gx; gi = gi < 0 ? 0 : (gi > NW - 1 ? NW - 1 : gi);
            int gj = (int)gy; gj = gj < 0 ? 0 : (gj > NH - 1 ? NH - 1 : gj);
            s_flat[tid] = (bn * NH + gj) * NW + gi;
        } else {
            sp1[tid] = make_float4(1e9f, -1e9f, 1e9f, -1e9f);  // empty box: inter=0
            sq[tid] = 0.0f;
            s_flat[tid] = -1;
        }
    }
    __syncthreads();
    if (tid == 0) {
        #pragma unroll
        for (int t = 0; t < NT; ++t) {
            int f = s_flat[t];
            if (f >= 0) s_map[f] = (unsigned char)(t + 1);
        }
    }
    __syncthreads();

    // ---- Phase 1: dense pass, 2 cells per thread ----
    const int c0 = blockIdx.x * 256 + tid;     // always < 9408 (19*256=4864)
    const int c1 = c0 + HALF;
    const bool v1 = (c1 < CELLS_PER_B);

    // cell 0
    const int a0 = c0 / HW;
    const int rem0 = c0 - a0 * HW;
    const int j0 = rem0 / NW;
    const int i0 = rem0 - j0 * NW;
    const float* base0 = out + (size_t)b * (NA * CH_PER_A * HW) + (size_t)(a0 * CH_PER_A) * HW + rem0;
    float o00 = base0[0];
    float o01 = base0[HW];
    float o02 = base0[2 * HW];
    float o03 = base0[3 * HW];
    float o04 = base0[4 * HW];

    // cell 1 (guarded loads; dummies otherwise)
    const int a1 = v1 ? (c1 / HW) : 0;
    const int rem1 = c1 - a1 * HW;
    const int j1 = rem1 / NW;
    const int i1 = rem1 - j1 * NW;
    float o10 = 0.f, o11 = 0.f, o12 = 0.f, o13 = 0.f, o14 = 0.f;
    const float* base1 = out + (size_t)b * (NA * CH_PER_A * HW) + (size_t)(a1 * CH_PER_A) * HW + rem1;
    if (v1) {
        o10 = base1[0];
        o11 = base1[HW];
        o12 = base1[2 * HW];
        o13 = base1[3 * HW];
        o14 = base1[4 * HW];
    }

    float x0 = fsig(o00), y0 = fsig(o01), conf0 = fsig(o04);
    float pw0 = __expf(o02) * aw[a0], ph0 = __expf(o03) * ah[a0];
    float px0 = x0 + (float)i0, py0 = y0 + (float)j0;
    float px1_0 = px0 - 0.5f * pw0, px2_0 = px0 + 0.5f * pw0;
    float py1_0 = py0 - 0.5f * ph0, py2_0 = py0 + 0.5f * ph0;
    float qp0 = 0.375f * pw0 * ph0;

    float x1 = fsig(o10), y1 = fsig(o11), conf1 = fsig(o14);
    float pw1 = __expf(o12) * aw[a1], ph1 = __expf(o13) * ah[a1];
    float px1c = x1 + (float)i1, py1c = y1 + (float)j1;
    float px1_1 = px1c - 0.5f * pw1, px2_1 = px1c + 0.5f * pw1;
    float py1_1 = py1c - 0.5f * ph1, py2_1 = py1c + 0.5f * ph1;
    float qp1 = 0.375f * pw1 * ph1;

    bool sil0 = false, sil1 = false;
    #pragma unroll 5
    for (int t = 0; t < NT; ++t) {
        float4 p1 = sp1[t];
        float qt = sq[t];
        float iw0 = fminf(p1.y, px2_0) - fmaxf(p1.x, px1_0);
        float ih0 = fminf(p1.w, py2_0) - fmaxf(p1.z, py1_0);
        float in0 = fmaxf(iw0, 0.f) * fmaxf(ih0, 0.f);
        sil0 = sil0 || (in0 > qt + qp0);
        float iw1 = fminf(p1.y, px2_1) - fmaxf(p1.x, px1_1);
        float ih1 = fminf(p1.w, py2_1) - fmaxf(p1.z, py1_1);
        float in1 = fmaxf(iw1, 0.f) * fmaxf(ih1, 0.f);
        sil1 = sil1 || (in1 > qt + qp1);
    }

    auto objloss = [&](int tsel, float x, float y, float o2, float o3, float conf,
                       float px1, float px2, float py1, float py2, float pw, float ph,
                       int i, int j, int a) -> float {
        float4 g1 = sp1[tsel];
        float gw = g1.y - g1.x, gh = g1.w - g1.z;
        float gx = 0.5f * (g1.x + g1.y), gy = 0.5f * (g1.z + g1.w);
        float tx = gx - (float)i, ty = gy - (float)j;
        float tw = __logf(gw) - law[a], th = __logf(gh) - lah[a];
        float l = 0.5f * ((x - tx) * (x - tx) + (y - ty) * (y - ty) +
                          (o2 - tw) * (o2 - tw) + (o3 - th) * (o3 - th));
        float iw = fminf(g1.y, px2) - fmaxf(g1.x, px1);
        float ih = fminf(g1.w, py2) - fmaxf(g1.z, py1);
        float inter = fmaxf(iw, 0.f) * fmaxf(ih, 0.f);
        float uni = gw * gh + pw * ph - inter;
        float tconf = inter / uni;
        l += 2.5f * (conf - tconf) * (conf - tconf);   // 0.5 * OBJECT_SCALE
        return l;
    };

    float lmain = 0.0f;
    {
        int m0 = (int)s_map[c0];
        if (m0 > 0) {
            int tsel = m0 - 1;
            lmain += objloss(tsel, x0, y0, o02, o03, conf0,
                             px1_0, px2_0, py1_0, py2_0, pw0, ph0, i0, j0, a0);
            int pos = atomicAdd(&s_cnt, 1);            // LDS atomic only
            s_obj[pos] = (c0 << 6) | tsel;
        } else {
            lmain += sil0 ? 0.0f : 0.5f * conf0 * conf0;
        }
    }
    if (v1) {
        int m1 = (int)s_map[c1];
        if (m1 > 0) {
            int tsel = m1 - 1;
            lmain += objloss(tsel, x1, y1, o12, o13, conf1,
                             px1_1, px2_1, py1_1, py2_1, pw1, ph1, i1, j1, a1);
            int pos = atomicAdd(&s_cnt, 1);
            s_obj[pos] = (c1 << 6) | tsel;
        } else {
            lmain += sil1 ? 0.0f : 0.5f * conf1 * conf1;
        }
    }
    __syncthreads();

    // ---- Phase 2: class loss, 3 objects x 80 classes per pass ----
    const int cnt = s_cnt;
    float lcls = 0.0f;
    if (cnt > 0) {
        const int oo = tid / NC;        // 0..3 (only <3 used)
        const int c = tid - oo * NC;
        if (oo < 3) {
            float w = cwt[c];
            float ew1 = __expf(w);
            float ew0 = __expf(1.0f - w);
            for (int o0 = 0; o0 < cnt; o0 += 3) {
                int o = o0 + oo;
                if (o < cnt) {
                    int pk = s_obj[o];
                    int olc = pk >> 6;
                    int tsel = pk & 63;
                    int a = olc / HW;
                    int rem = olc - a * HW;
                    float p = fsig(out[(size_t)b * (NA * CH_PER_A * HW) +
                                       (size_t)(a * CH_PER_A + 5 + c) * HW + rem]);
                    float t = tcls[(size_t)(b * NT + tsel) * NC + c];
                    float l1 = sqrtf(1.0f - p + EPSF) * __logf(p + EPSF) * ew1;
                    float l0 = sqrtf(p + EPSF) * __logf(1.0f - p + EPSF) * ew0;
                    lcls += t * l1 + (1.0f - t) * l0;
                }
            }
        }
    }

    // ---- Phase 3: block reduction -> one float4 partial per block ----
    for (int off = 32; off > 0; off >>= 1) {
        lmain += __shfl_down(lmain, off, 64);
        lcls  += __shfl_down(lcls, off, 64);
    }
    if ((tid & 63) == 0) { redm[tid >> 6] = lmain; redc[tid >> 6] = lcls; }
    __syncthreads();
    if (tid == 0) {
        float m = redm[0] + redm[1] + redm[2] + redm[3];
        float c = redc[0] + redc[1] + redc[2] + redc[3];
        part[blockIdx.y * NBX + blockIdx.x] = make_float4(m, c, (float)cnt, 0.0f);
    }
}

// ---------------------------------------------------------------------------
// Finalize: one block reduces the 608 float4 partials.
// ---------------------------------------------------------------------------
__global__ __launch_bounds__(256) void finalize_kernel(const float4* __restrict__ part,
                                                       float* __restrict__ outp) {
    const int tid = threadIdx.x;
    float m = 0.0f, c = 0.0f, n = 0.0f;
    for (int i = tid; i < NBLK; i += 256) {
        float4 p = part[i];
        m += p.x; c += p.y; n += p.z;
    }
    for (int off = 32; off > 0; off >>= 1) {
        m += __shfl_down(m, off, 64);
        c += __shfl_down(c, off, 64);
        n += __shfl_down(n, off, 64);
    }
    __shared__ float rm[4], rc[4], rn[4];
    if ((tid & 63) == 0) { rm[tid >> 6] = m; rc[tid >> 6] = c; rn[tid >> 6] = n; }
    __syncthreads();
    if (tid == 0) {
        float ms = rm[0] + rm[1] + rm[2] + rm[3];
        float cs = rc[0] + rc[1] + rc[2] + rc[3];
        float ns = rn[0] + rn[1] + rn[2] + rn[3];
        float nsel = fmaxf(ns, 1.0f);
        outp[0] = ms - cs / nsel;
    }
}

extern "C" void kernel_launch(void* const* d_in, const int* in_sizes, int n_in,
                              void* d_out, int out_size, void* d_ws, size_t ws_size,
                              hipStream_t stream) {
    const float* output = (const float*)d_in[0];
    const float* tb     = (const float*)d_in[1];
    const float* tcls   = (const float*)d_in[2];
    const float* cwt    = (const float*)d_in[3];

    float4* part = (float4*)d_ws;           // NBLK * 16B = 9728 B

    fused_kernel<<<dim3(NBX, NB), 256, 0, stream>>>(output, tb, tcls, cwt, part);
    finalize_kernel<<<1, 256, 0, stream>>>(part, (float*)d_out);
}

// Round 6
// 20.190 us; speedup vs baseline: 1.1002x; 1.1002x over previous
//
#include <hip/hip_runtime.h>
#include <math.h>

#define NB 32
#define NA 3
#define NC 80
#define NH 56
#define NW 56
#define NT 50
#define HW (NH*NW)              // 3136
#define CELLS_PER_B (NA*HW)     // 9408
#define CH_PER_A (5+NC)         // 85
#define EPSF 1e-7f
#define NBX ((CELLS_PER_B + 255) / 256)   // 37
#define NBLK (NBX*NB)                     // 1184

__device__ __forceinline__ float fsig(float v) { return 1.0f / (1.0f + __expf(-v)); }

// ---------------------------------------------------------------------------
// Fused kernel. grid (37, 32), block 256, 1 cell/thread (max parallelism).
// Phase 0: prep 50 targets into LDS (boxes as corners + prescaled area + flat).
// Phase 1: dense pass — min/max-form intersection, silence test without
//          division, per-iter flat==lc compare for target selection
//          (last-t wins == .at[].set duplicate semantics).
// Phase 2: class focal loss for this block's object cells (3 obj x 80 cls).
// Phase 3: block reduce -> one float4 partial per block (no global atomics).
// ---------------------------------------------------------------------------
__global__ __launch_bounds__(256) void fused_kernel(const float* __restrict__ out,
                                                    const float* __restrict__ tb,
                                                    const float* __restrict__ tcls,
                                                    const float* __restrict__ cwt,
                                                    float4* __restrict__ part) {
    __shared__ float4 sp1[NT];                 // {x1, x2, y1, y2}
    __shared__ float2 sqf[NT];                 // {0.375*area, flat_as_bits}
    __shared__ int    s_obj[NT];
    __shared__ int    s_cnt;
    __shared__ float  redm[4], redc[4];

    const int b = blockIdx.y;
    const int tid = threadIdx.x;

    const float aw[3]  = {1.28967f, 2.12714f, 3.27212f};
    const float ah[3]  = {4.15014f, 5.09344f, 5.87423f};
    const float law[3] = {0.25438842f, 0.75477730f, 1.18543813f};   // ln(aw)
    const float lah[3] = {1.42314173f, 1.62795138f, 1.77057764f};   // ln(ah)

    // ---- Phase 0: prep this batch's 50 targets into LDS ----
    if (tid == 0) s_cnt = 0;
    if (tid < NT) {
        float4 box = ((const float4*)tb)[b * NT + tid];
        if (box.z > 0.0f) {
            float gx = box.x * (float)NW;
            float gy = box.y * (float)NH;
            float gw = box.z * (float)NW;
            float gh = box.w * (float)NH;
            sp1[tid] = make_float4(gx - 0.5f * gw, gx + 0.5f * gw,
                                   gy - 0.5f * gh, gy + 0.5f * gh);
            int bn = 0; float best = -1.0f;
            #pragma unroll
            for (int k = 0; k < 3; ++k) {
                float inter = fminf(aw[k], gw) * fminf(ah[k], gh);
                float uni = aw[k] * ah[k] + gw * gh - inter;
                float r = inter / uni;
                if (r > best) { best = r; bn = k; }
            }
            int gi = (int)gx; gi = gi < 0 ? 0 : (gi > NW - 1 ? NW - 1 : gi);
            int gj = (int)gy; gj = gj < 0 ? 0 : (gj > NH - 1 ? NH - 1 : gj);
            int flat = (bn * NH + gj) * NW + gi;
            sqf[tid] = make_float2(0.375f * gw * gh, __int_as_float(flat));
        } else {
            sp1[tid] = make_float4(1e9f, -1e9f, 1e9f, -1e9f);  // empty: inter=0, no NaN
            sqf[tid] = make_float2(0.0f, __int_as_float(-1));
        }
    }
    __syncthreads();

    // ---- Phase 1: dense pass ----
    const int lc = blockIdx.x * 256 + tid;
    float lmain = 0.0f;

    if (lc < CELLS_PER_B) {
        const int a = lc / HW;
        const int rem = lc - a * HW;
        const int j = rem / NW;
        const int i = rem - j * NW;

        const float* base = out + (size_t)b * (NA * CH_PER_A * HW) + (size_t)(a * CH_PER_A) * HW + rem;
        float o0 = base[0];
        float o1 = base[HW];
        float o2 = base[2 * HW];
        float o3 = base[3 * HW];
        float o4 = base[4 * HW];

        float x = fsig(o0);
        float y = fsig(o1);
        float conf = fsig(o4);
        float pw = __expf(o2) * aw[a];
        float ph = __expf(o3) * ah[a];
        float px = x + (float)i;
        float py = y + (float)j;
        float px1 = px - 0.5f * pw, px2 = px + 0.5f * pw;
        float py1 = py - 0.5f * ph, py2 = py + 0.5f * ph;
        float qp = 0.375f * (pw * ph);

        bool sil = false;
        int tsel = -1;
        #pragma unroll 5
        for (int t = 0; t < NT; ++t) {
            float4 p1 = sp1[t];
            float2 qf = sqf[t];
            float iw = fminf(p1.y, px2) - fmaxf(p1.x, px1);
            float ih = fminf(p1.w, py2) - fmaxf(p1.z, py1);
            float in = fmaxf(iw, 0.f) * fmaxf(ih, 0.f);
            // iou > 0.6  <=>  inter > 0.375*(areaT + areaP)
            sil = sil || (in > qf.x + qp);
            if (__float_as_int(qf.y) == lc) tsel = t;   // last t wins
        }

        if (tsel >= 0) {
            float4 g1 = sp1[tsel];
            float gw = g1.y - g1.x, gh = g1.w - g1.z;
            float gx = 0.5f * (g1.x + g1.y), gy = 0.5f * (g1.z + g1.w);
            float tx = gx - (float)i, ty = gy - (float)j;
            float tw = __logf(gw) - law[a], th = __logf(gh) - lah[a];
            lmain += 0.5f * ((x - tx) * (x - tx) + (y - ty) * (y - ty) +
                             (o2 - tw) * (o2 - tw) + (o3 - th) * (o3 - th));
            float iw = fminf(g1.y, px2) - fmaxf(g1.x, px1);
            float ih = fminf(g1.w, py2) - fmaxf(g1.z, py1);
            float inter = fmaxf(iw, 0.f) * fmaxf(ih, 0.f);
            float uni = gw * gh + pw * ph - inter;
            float tconf = inter / uni;
            lmain += 2.5f * (conf - tconf) * (conf - tconf);   // 0.5 * OBJECT_SCALE

            int pos = atomicAdd(&s_cnt, 1);                     // LDS atomic only
            s_obj[pos] = (lc << 6) | tsel;
        } else {
            lmain += sil ? 0.0f : 0.5f * conf * conf;
        }
    }
    __syncthreads();

    // ---- Phase 2: class loss, 3 objects x 80 classes per pass ----
    const int cnt = s_cnt;
    float lcls = 0.0f;
    if (cnt > 0) {
        const int oo = tid / NC;        // 0..3 (only <3 used)
        const int c = tid - oo * NC;
        if (oo < 3) {
            float w = cwt[c];
            float ew1 = __expf(w);
            float ew0 = __expf(1.0f - w);
            for (int o0 = 0; o0 < cnt; o0 += 3) {
                int o = o0 + oo;
                if (o < cnt) {
                    int pk = s_obj[o];
                    int olc = pk >> 6;
                    int tsel = pk & 63;
                    int a = olc / HW;
                    int rem = olc - a * HW;
                    float p = fsig(out[(size_t)b * (NA * CH_PER_A * HW) +
                                       (size_t)(a * CH_PER_A + 5 + c) * HW + rem]);
                    float t = tcls[(size_t)(b * NT + tsel) * NC + c];
                    float l1 = sqrtf(1.0f - p + EPSF) * __logf(p + EPSF) * ew1;
                    float l0 = sqrtf(p + EPSF) * __logf(1.0f - p + EPSF) * ew0;
                    lcls += t * l1 + (1.0f - t) * l0;
                }
            }
        }
    }

    // ---- Phase 3: block reduction -> one float4 partial per block ----
    for (int off = 32; off > 0; off >>= 1) {
        lmain += __shfl_down(lmain, off, 64);
        lcls  += __shfl_down(lcls, off, 64);
    }
    if ((tid & 63) == 0) { redm[tid >> 6] = lmain; redc[tid >> 6] = lcls; }
    __syncthreads();
    if (tid == 0) {
        float m = redm[0] + redm[1] + redm[2] + redm[3];
        float c = redc[0] + redc[1] + redc[2] + redc[3];
        part[blockIdx.y * NBX + blockIdx.x] = make_float4(m, c, (float)cnt, 0.0f);
    }
}

// ---------------------------------------------------------------------------
// Finalize: one block reduces the 1184 float4 partials.
// ---------------------------------------------------------------------------
__global__ __launch_bounds__(256) void finalize_kernel(const float4* __restrict__ part,
                                                       float* __restrict__ outp) {
    const int tid = threadIdx.x;
    float m = 0.0f, c = 0.0f, n = 0.0f;
    for (int i = tid; i < NBLK; i += 256) {
        float4 p = part[i];
        m += p.x; c += p.y; n += p.z;
    }
    for (int off = 32; off > 0; off >>= 1) {
        m += __shfl_down(m, off, 64);
        c += __shfl_down(c, off, 64);
        n += __shfl_down(n, off, 64);
    }
    __shared__ float rm[4], rc[4], rn[4];
    if ((tid & 63) == 0) { rm[tid >> 6] = m; rc[tid >> 6] = c; rn[tid >> 6] = n; }
    __syncthreads();
    if (tid == 0) {
        float ms = rm[0] + rm[1] + rm[2] + rm[3];
        float cs = rc[0] + rc[1] + rc[2] + rc[3];
        float ns = rn[0] + rn[1] + rn[2] + rn[3];
        float nsel = fmaxf(ns, 1.0f);
        outp[0] = ms - cs / nsel;
    }
}

extern "C" void kernel_launch(void* const* d_in, const int* in_sizes, int n_in,
                              void* d_out, int out_size, void* d_ws, size_t ws_size,
                              hipStream_t stream) {
    const float* output = (const float*)d_in[0];
    const float* tb     = (const float*)d_in[1];
    const float* tcls   = (const float*)d_in[2];
    const float* cwt    = (const float*)d_in[3];

    float4* part = (float4*)d_ws;           // NBLK * 16B = 18944 B

    fused_kernel<<<dim3(NBX, NB), 256, 0, stream>>>(output, tb, tcls, cwt, part);
    finalize_kernel<<<1, 256, 0, stream>>>(part, (float*)d_out);
}

// Round 7
// 19.184 us; speedup vs baseline: 1.1579x; 1.0524x over previous
//
#include <hip/hip_runtime.h>
#include <math.h>

#define NB 32
#define NA 3
#define NC 80
#define NH 56
#define NW 56
#define NT 50
#define HW (NH*NW)              // 3136
#define CELLS_PER_B (NA*HW)     // 9408
#define CH_PER_A (5+NC)         // 85
#define EPSF 1e-7f
#define NBX ((CELLS_PER_B + 255) / 256)   // 37
#define NBLK (NBX*NB)                     // 1184

__device__ __forceinline__ float fsig(float v) { return 1.0f / (1.0f + __expf(-v)); }

// ---------------------------------------------------------------------------
// Fused kernel. grid (37, 32), block 256, 1 cell/thread.
// Phase 0: prep 50 targets into LDS + per-block cell->target ownership map
//          built with LDS atomicMax (max-t == last-t-wins == .at[].set).
// Then: tsel known EARLY -> issue the uncoalesced 80-class gather loads
//       BEFORE the silence t-loop so their latency hides under it.
// Phase 1: silence-only t-loop (b128+b32 LDS broadcast + 10 VALU).
// Phase 2: consume prefetched class data; rare extra objects post-loop.
// Phase 3: block reduce -> one float4 partial per block (no global atomics).
// ---------------------------------------------------------------------------
__global__ __launch_bounds__(256) void fused_kernel(const float* __restrict__ out,
                                                    const float* __restrict__ tb,
                                                    const float* __restrict__ tcls,
                                                    const float* __restrict__ cwt,
                                                    float4* __restrict__ part) {
    __shared__ float4 sp1[NT];        // {x1, x2, y1, y2}
    __shared__ float  sq[NT];         // 0.375 * area_t
    __shared__ int    s_map[256];     // cell-in-block -> t+1 (0 = none)
    __shared__ int    s_obj[NT];
    __shared__ int    s_cnt;
    __shared__ float  redm[4], redc[4];

    const int b = blockIdx.y;
    const int tid = threadIdx.x;
    const int block_lo = blockIdx.x * 256;
    const int lc = block_lo + tid;
    const size_t bofs = (size_t)b * (NA * CH_PER_A * HW);

    const float aw[3]  = {1.28967f, 2.12714f, 3.27212f};
    const float ah[3]  = {4.15014f, 5.09344f, 5.87423f};
    const float law[3] = {0.25438842f, 0.75477730f, 1.18543813f};   // ln(aw)
    const float lah[3] = {1.42314173f, 1.62795138f, 1.77057764f};   // ln(ah)

    // ---- issue dense o-loads as early as possible ----
    const int a = lc / HW;
    const int rem = lc - a * HW;
    const int j = rem / NW;
    const int i = rem - j * NW;
    float o0 = 0.f, o1 = 0.f, o2 = 0.f, o3 = 0.f, o4 = 0.f;
    const bool cv = (lc < CELLS_PER_B);
    if (cv) {
        const float* base = out + bofs + (size_t)(a * CH_PER_A) * HW + rem;
        o0 = base[0];
        o1 = base[HW];
        o2 = base[2 * HW];
        o3 = base[3 * HW];
        o4 = base[4 * HW];
    }

    // ---- Phase 0: targets + ownership map ----
    s_map[tid] = 0;
    if (tid == 0) s_cnt = 0;
    int myflat = -1;
    if (tid < NT) {
        float4 box = ((const float4*)tb)[b * NT + tid];
        if (box.z > 0.0f) {
            float gx = box.x * (float)NW;
            float gy = box.y * (float)NH;
            float gw = box.z * (float)NW;
            float gh = box.w * (float)NH;
            sp1[tid] = make_float4(gx - 0.5f * gw, gx + 0.5f * gw,
                                   gy - 0.5f * gh, gy + 0.5f * gh);
            sq[tid] = 0.375f * gw * gh;
            int bn = 0; float best = -1.0f;
            #pragma unroll
            for (int k = 0; k < 3; ++k) {
                float inter = fminf(aw[k], gw) * fminf(ah[k], gh);
                float uni = aw[k] * ah[k] + gw * gh - inter;
                float r = inter / uni;
                if (r > best) { best = r; bn = k; }
            }
            int gi = (int)gx; gi = gi < 0 ? 0 : (gi > NW - 1 ? NW - 1 : gi);
            int gj = (int)gy; gj = gj < 0 ? 0 : (gj > NH - 1 ? NH - 1 : gj);
            myflat = (bn * NH + gj) * NW + gi;
        } else {
            sp1[tid] = make_float4(1e9f, -1e9f, 1e9f, -1e9f);  // empty: inter<=0
            sq[tid] = 0.0f;
        }
    }
    __syncthreads();                                   // map zeroed, targets in LDS
    if (myflat >= block_lo && myflat < block_lo + 256)
        atomicMax(&s_map[myflat - block_lo], tid + 1); // max-t == last-t-wins
    __syncthreads();

    // ---- own-cell target selection + object registration ----
    const int tsel = s_map[tid] - 1;                   // -1 = non-object
    if (tsel >= 0) {
        int pos = atomicAdd(&s_cnt, 1);                // LDS atomic only
        s_obj[pos] = (tid << 8) | tsel;
    }
    __syncthreads();

    // ---- early-issue class gather for first 3 objects (latency hides under t-loop) ----
    const int cnt = s_cnt;
    const int oo = tid / NC;            // 0..3 (only <3 used)
    const int cc = tid - oo * NC;       // class index
    float praw = 0.f, traw = 0.f, wcls = 0.f;
    bool gv = false;
    int golc = 0;
    if (oo < 3 && oo < cnt) {
        int pk = s_obj[oo];
        golc = block_lo + (pk >> 8);
        int gts = pk & 255;
        int ga = golc / HW;
        int grem = golc - ga * HW;
        praw = out[bofs + (size_t)(ga * CH_PER_A + 5 + cc) * HW + grem];
        traw = tcls[(size_t)(b * NT + (pk & 255)) * NC + cc];
        wcls = cwt[cc];
        (void)gts;
        gv = true;
    }

    // ---- pred box ----
    float x = fsig(o0);
    float y = fsig(o1);
    float conf = fsig(o4);
    float pw = __expf(o2) * aw[a < 3 ? a : 0];
    float ph = __expf(o3) * ah[a < 3 ? a : 0];
    float px = x + (float)i;
    float py = y + (float)j;
    float px1 = px - 0.5f * pw, px2 = px + 0.5f * pw;
    float py1 = py - 0.5f * ph, py2 = py + 0.5f * ph;
    float qp = 0.375f * (pw * ph);

    // ---- Phase 1: silence-only t-loop ----
    bool sil = false;
    #pragma unroll 5
    for (int t = 0; t < NT; ++t) {
        float4 p1 = sp1[t];
        float qt = sq[t];
        float iw = fminf(p1.y, px2) - fmaxf(p1.x, px1);
        float ih = fminf(p1.w, py2) - fmaxf(p1.z, py1);
        float in = fmaxf(iw, 0.f) * fmaxf(ih, 0.f);
        sil = sil || (in > qt + qp);   // iou>0.6 <=> inter > 0.375*(At+Ap)
    }

    // ---- dense losses ----
    float lmain = 0.0f;
    if (cv) {
        if (tsel >= 0) {
            float4 g1 = sp1[tsel];
            float gw = g1.y - g1.x, gh = g1.w - g1.z;
            float gx = 0.5f * (g1.x + g1.y), gy = 0.5f * (g1.z + g1.w);
            float tx = gx - (float)i, ty = gy - (float)j;
            float tw = __logf(gw) - law[a], th = __logf(gh) - lah[a];
            lmain += 0.5f * ((x - tx) * (x - tx) + (y - ty) * (y - ty) +
                             (o2 - tw) * (o2 - tw) + (o3 - th) * (o3 - th));
            float iw = fminf(g1.y, px2) - fmaxf(g1.x, px1);
            float ih = fminf(g1.w, py2) - fmaxf(g1.z, py1);
            float inter = fmaxf(iw, 0.f) * fmaxf(ih, 0.f);
            float uni = gw * gh + pw * ph - inter;
            float tconf = inter / uni;
            lmain += 2.5f * (conf - tconf) * (conf - tconf);   // 0.5*OBJECT_SCALE
        } else {
            lmain += sil ? 0.0f : 0.5f * conf * conf;
        }
    }

    // ---- Phase 2: focal class loss (prefetched first 3 objects; rare rest) ----
    float lcls = 0.0f;
    if (gv) {
        float p = fsig(praw);
        float ew1 = __expf(wcls);
        float ew0 = __expf(1.0f - wcls);
        float l1 = sqrtf(1.0f - p + EPSF) * __logf(p + EPSF) * ew1;
        float l0 = sqrtf(p + EPSF) * __logf(1.0f - p + EPSF) * ew0;
        lcls += traw * l1 + (1.0f - traw) * l0;
    }
    if (oo < 3) {
        for (int o = oo + 3; o < cnt; o += 3) {        // rare: >3 objects/block
            int pk = s_obj[o];
            int olc2 = block_lo + (pk >> 8);
            int a2 = olc2 / HW;
            int rem2 = olc2 - a2 * HW;
            float p = fsig(out[bofs + (size_t)(a2 * CH_PER_A + 5 + cc) * HW + rem2]);
            float t2 = tcls[(size_t)(b * NT + (pk & 255)) * NC + cc];
            float w = cwt[cc];
            float l1 = sqrtf(1.0f - p + EPSF) * __logf(p + EPSF) * __expf(w);
            float l0 = sqrtf(p + EPSF) * __logf(1.0f - p + EPSF) * __expf(1.0f - w);
            lcls += t2 * l1 + (1.0f - t2) * l0;
        }
    }

    // ---- Phase 3: block reduction -> one float4 partial per block ----
    for (int off = 32; off > 0; off >>= 1) {
        lmain += __shfl_down(lmain, off, 64);
        lcls  += __shfl_down(lcls, off, 64);
    }
    if ((tid & 63) == 0) { redm[tid >> 6] = lmain; redc[tid >> 6] = lcls; }
    __syncthreads();
    if (tid == 0) {
        float m = redm[0] + redm[1] + redm[2] + redm[3];
        float c = redc[0] + redc[1] + redc[2] + redc[3];
        part[blockIdx.y * NBX + blockIdx.x] = make_float4(m, c, (float)cnt, 0.0f);
    }
}

// ---------------------------------------------------------------------------
// Finalize: one block reduces the 1184 float4 partials.
// ---------------------------------------------------------------------------
__global__ __launch_bounds__(256) void finalize_kernel(const float4* __restrict__ part,
                                                       float* __restrict__ outp) {
    const int tid = threadIdx.x;
    float m = 0.0f, c = 0.0f, n = 0.0f;
    for (int i = tid; i < NBLK; i += 256) {
        float4 p = part[i];
        m += p.x; c += p.y; n += p.z;
    }
    for (int off = 32; off > 0; off >>= 1) {
        m += __shfl_down(m, off, 64);
        c += __shfl_down(c, off, 64);
        n += __shfl_down(n, off, 64);
    }
    __shared__ float rm[4], rc[4], rn[4];
    if ((tid & 63) == 0) { rm[tid >> 6] = m; rc[tid >> 6] = c; rn[tid >> 6] = n; }
    __syncthreads();
    if (tid == 0) {
        float ms = rm[0] + rm[1] + rm[2] + rm[3];
        float cs = rc[0] + rc[1] + rc[2] + rc[3];
        float ns = rn[0] + rn[1] + rn[2] + rn[3];
        float nsel = fmaxf(ns, 1.0f);
        outp[0] = ms - cs / nsel;
    }
}

extern "C" void kernel_launch(void* const* d_in, const int* in_sizes, int n_in,
                              void* d_out, int out_size, void* d_ws, size_t ws_size,
                              hipStream_t stream) {
    const float* output = (const float*)d_in[0];
    const float* tb     = (const float*)d_in[1];
    const float* tcls   = (const float*)d_in[2];
    const float* cwt    = (const float*)d_in[3];

    float4* part = (float4*)d_ws;           // NBLK * 16B = 18944 B

    fused_kernel<<<dim3(NBX, NB), 256, 0, stream>>>(output, tb, tcls, cwt, part);
    finalize_kernel<<<1, 256, 0, stream>>>(part, (float*)d_out);
}